// Round 17
// baseline (306.941 us; speedup 1.0000x reference)
//
#include <hip/hip_runtime.h>
#include <hip/hip_bf16.h>
#include <stdint.h>

// S=1024, B=4, H=1024, N=16, D=64. Causal relative attention (TXL-style).
// ws layout (MB):
//   0  Xb   bf16 [4096][1024]          (later aliased as AVb)
//   8  Pb   bf16 rows0..4100 [.][1024] (pos)
//  24  WT3  bf16 [3072][1024]
//  30  WrT  bf16 [1024][1024]
//  32  Wob  bf16 [1024][1024]
//  34  Qb   bf16 [64bn][1024i][64d]
//  42  Kb   bf16 [64bn][1024j][64d]
//  50  VTb  bf16 [64bn][64d][1024j]
//  58  Rb   bf16 [64bn][1024dist][64d]   R[dist]=kr[S-dist]
//  66  efb  f32  [64bn][1024i]   de only, pre-scaled by 0.125*log2e
//  66.5 dpw u64  [4b][1024i][16jt]
//  67  lsb  f32  [2560pid][64row]        (l only; m == 0 globally)
//  69  pOb  bf16 [2560pid][64row][64d]   (21MB; base doubles as Vtmp before attn)
//
// m == 0 softmax (scores bounded by construction). e0 cancels in softmax.
// dpackw rides inside the fused-GEMM launch; that launch is XCD-swizzled
// (5120 blocks = 8*640, bijective) so blocks sharing an L-panel are L2-local.

typedef short short8 __attribute__((ext_vector_type(8)));
typedef __bf16 bf16x8 __attribute__((ext_vector_type(8)));
typedef float f32x4 __attribute__((ext_vector_type(4)));
typedef unsigned short u16;
typedef unsigned long long u64;

#define LOG2E 1.4426950408889634f

__device__ __forceinline__ u16 f2bf(float f) {
  union { float f; unsigned u; } v; v.f = f;
  unsigned u = v.u;
  u += 0x7fffu + ((u >> 16) & 1u);
  return (u16)(u >> 16);
}
__device__ __forceinline__ float bf2f(u16 h) {
  union { unsigned u; float f; } v; v.u = ((unsigned)h) << 16;
  return v.f;
}
__device__ __forceinline__ unsigned cvt_pk(float lo, float hi) {
  unsigned r;
  asm("v_cvt_pk_bf16_f32 %0, %1, %2" : "=v"(r) : "v"(lo), "v"(hi));
  return r;
}

__device__ __forceinline__ f32x4 MFMA(short8 a, short8 b, f32x4 c) {
  union { short8 s; bf16x8 v; } ua, ub;
  ua.s = a; ub.s = b;
  return __builtin_amdgcn_mfma_f32_16x16x32_bf16(ua.v, ub.v, c, 0, 0, 0);
}

__device__ __forceinline__ void gload16(const void* g, void* l) {
  __builtin_amdgcn_global_load_lds(
      (const __attribute__((address_space(1))) unsigned int*)g,
      (__attribute__((address_space(3))) unsigned int*)l, 16, 0, 0);
}

// ---------------- fused prep: cvt(pos,X,Wo) + transpose(Wq,Wk,Wv,Wr) ----------------
__global__ void k_prep(const float* __restrict__ pos, const float* __restrict__ X,
                       const float* __restrict__ Wo, const float* __restrict__ Wq,
                       const float* __restrict__ Wk, const float* __restrict__ Wv,
                       const float* __restrict__ Wr,
                       u16* __restrict__ Pb, u16* __restrict__ Xb, u16* __restrict__ Wob,
                       u16* __restrict__ WT3, u16* __restrict__ WrT) {
  int bid = blockIdx.x;
  int tid = threadIdx.x;
  if (bid < 9221) {
    const float* in; u16* out; int n, base;
    if (bid < 4101)      { in = pos; out = Pb;  n = 4198400; base = bid; }
    else if (bid < 8197) { in = X;   out = Xb;  n = 4194304; base = bid - 4101; }
    else                 { in = Wo;  out = Wob; n = 1048576; base = bid - 8197; }
    int i = (base * 256 + tid) * 4;
    if (i >= n) return;
    float4 f = *reinterpret_cast<const float4*>(in + i);
    ushort4 o;
    o.x = f2bf(f.x); o.y = f2bf(f.y); o.z = f2bf(f.z); o.w = f2bf(f.w);
    *reinterpret_cast<ushort4*>(out + i) = o;
  } else {
    __shared__ float tile[32][33];
    int tb = bid - 9221;
    int which = tb >> 10;
    int by = (tb >> 5) & 31, bx = tb & 31;
    const float* src = (which == 0) ? Wq : (which == 1) ? Wk : (which == 2) ? Wv : Wr;
    u16* dst = (which < 3) ? (WT3 + (size_t)which * 1048576) : WrT;
    int c0 = bx * 32, h0 = by * 32;
    int tx = tid & 31, ty = tid >> 5;
    for (int r = 0; r < 32; r += 8)
      tile[ty + r][tx] = src[(size_t)(h0 + ty + r) * 1024 + c0 + tx];
    __syncthreads();
    for (int r = 0; r < 32; r += 8)
      dst[(size_t)(c0 + ty + r) * 1024 + h0 + tx] = f2bf(tile[tx][ty + r]);
  }
}

// ---------------- fused mid: k_vt (blocks [0,1024)) + k_ef (blocks [1024,1280)) ----------------
__global__ void k_mid(const u16* __restrict__ V, u16* __restrict__ VT,
                      const u16* __restrict__ Q, const float* __restrict__ rsb,
                      const float* __restrict__ segE, float* __restrict__ ef) {
  int bid = blockIdx.x;
  int tid = threadIdx.x;
  if (bid < 1024) {
    __shared__ u16 t[64][68];
    int i0 = (bid & 15) * 64;
    int bn = bid >> 4;
    int tx = tid & 63, ty = tid >> 6;
#pragma unroll
    for (int q = 0; q < 16; q++) {
      int il = ty * 16 + q;
      t[il][tx] = V[(size_t)((bn << 10) + i0 + il) * 64 + tx];
    }
    __syncthreads();
#pragma unroll
    for (int q = 0; q < 16; q++) {
      int d = ty * 16 + q;
      VT[(((size_t)((bn << 6) | d)) << 10) + i0 + tx] = t[tx][d];
    }
  } else {
    int idx = (bid - 1024) * 256 + tid;
    int n = (idx >> 10) & 15;
    float s0 = 0.f, s1 = 0.f;
    const short8* qrow = reinterpret_cast<const short8*>(Q + ((size_t)idx) * 64);
#pragma unroll
    for (int c = 0; c < 8; c++) {
      short8 v = qrow[c];
#pragma unroll
      for (int e = 0; e < 8; e++) {
        int d = c * 8 + e;
        float qv = bf2f((u16)v[e]) + rsb[n * 64 + d];
        s0 += qv * segE[n * 64 + d];
        s1 += qv * segE[1024 + n * 64 + d];
      }
    }
    ef[idx] = (s1 - s0) * (0.125f * LOG2E);
  }
}

// ---------------- fused GEMM (128x128 tile) + dpackw riders, XCD-swizzled ----------------
// logical grid (32, 160): y<24 mode0 (Xb@WT3 -> Q/K/V), y in [24,32) mode1
// (Pb remapped @ WrT -> Rb), y>=32 dpackw riders (seg_mat -> dpw).
__device__ __forceinline__ int srcA_g(int mode, int row, int kk) {
  if (mode == 0) return row * 1024 + kk;
  if (mode == 1) return ((1024 - (row >> 2)) * 4 + (row & 3)) * 1024 + kk;
  int i = row >> 2, b = row & 3, n = kk >> 6, d = kk & 63;
  return (((b << 4) | n) * 1024 + i) * 64 + d;
}

__global__ __launch_bounds__(256, 2) void k_gemmF(const u16* __restrict__ A0,
                                                  const u16* __restrict__ L0,
                                                  const u16* __restrict__ A1,
                                                  const u16* __restrict__ L1,
                                                  u16* __restrict__ outQ,
                                                  u16* __restrict__ outK,
                                                  u16* __restrict__ outV,
                                                  u16* __restrict__ outR,
                                                  const float* __restrict__ seg,
                                                  u64* __restrict__ dpw) {
  __shared__ u16 At[128 * 32];
  __shared__ u16 Lt[128 * 32];
  int tid = threadIdx.x;
  // XCD-bijective swizzle: 5120 blocks = 8 XCDs x 640 contiguous
  int f = blockIdx.x + 32 * blockIdx.y;
  int wg = (f & 7) * 640 + (f >> 3);
  int bx = wg & 31, by = wg >> 5;
  if (by >= 32) {
    // dpackw rider: one wave per (i,jt); coalesced 32B/lane, 4 ballots.
    int tb = (by - 32) * 32 + bx;   // [0,4096)
    int W = tb * 4 + (tid >> 6);
    int lane = tid & 63;
    int jt = W & 15, i = W >> 4;
    const float4* p = reinterpret_cast<const float4*>(
        seg + ((size_t)((i << 10) + (jt << 6) + lane)) * 8);
    float4 a = p[0], bq = p[1];
    u64 m0 = __ballot(a.y != 0.f);
    u64 m1 = __ballot(a.w != 0.f);
    u64 m2 = __ballot(bq.y != 0.f);
    u64 m3 = __ballot(bq.w != 0.f);
    if (lane == 0) {
      int o = (i << 4) + jt;
      dpw[o] = m0;
      dpw[16384 + o] = m1;
      dpw[32768 + o] = m2;
      dpw[49152 + o] = m3;
    }
    return;
  }
  int mode, n0;
  const u16 *A, *L;
  if (by < 24) { mode = 0; n0 = by * 128; A = A0; L = L0; }
  else         { mode = 1; n0 = (by - 24) * 128; A = A1; L = L1; }
  int m0 = bx * 128;
  int w = tid >> 6, lane = tid & 63;
  int lr = lane & 15, lg = lane >> 4;
  int wr = w >> 1, wc = w & 1;
  f32x4 acc[4][4] = {};

  for (int k0 = 0; k0 < 1024; k0 += 32) {
    for (int cc = 0; cc < 2; cc++) {
      int slot = cc * 256 + w * 64 + lane;
      int row = slot >> 2, ch = slot & 3;
      int sch = ch ^ ((row >> 1) & 3);
      gload16(A + srcA_g(mode, m0 + row, k0 + sch * 8), &At[(cc * 256 + w * 64) * 8]);
      gload16(L + (size_t)(n0 + row) * 1024 + k0 + sch * 8, &Lt[(cc * 256 + w * 64) * 8]);
    }
    __syncthreads();
    short8 af[4], bfr[4];
    for (int mt = 0; mt < 4; mt++) {
      int rr = wr * 64 + mt * 16 + lr;
      af[mt] = *reinterpret_cast<const short8*>(&At[rr * 32 + ((lg ^ ((rr >> 1) & 3)) * 8)]);
    }
    for (int ct = 0; ct < 4; ct++) {
      int rr = wc * 64 + ct * 16 + lr;
      bfr[ct] = *reinterpret_cast<const short8*>(&Lt[rr * 32 + ((lg ^ ((rr >> 1) & 3)) * 8)]);
    }
    for (int mt = 0; mt < 4; mt++)
      for (int ct = 0; ct < 4; ct++)
        acc[mt][ct] = MFMA(af[mt], bfr[ct], acc[mt][ct]);
    __syncthreads();
  }

  for (int mt = 0; mt < 4; mt++)
    for (int ct = 0; ct < 4; ct++)
      for (int r = 0; r < 4; r++) {
        int row = m0 + wr * 64 + mt * 16 + lg * 4 + r;
        int col = n0 + wc * 64 + ct * 16 + lr;
        float v = acc[mt][ct][r];
        if (mode == 0) {
          int i = row >> 2, b = row & 3;
          int which = col >> 10, nd = col & 1023, n = nd >> 6, d = nd & 63;
          u16 hv = f2bf(v);
          int bn = (b << 4) | n;
          if (which == 0)       outQ[(size_t)(bn * 1024 + i) * 64 + d] = hv;
          else if (which == 1)  outK[(size_t)(bn * 1024 + i) * 64 + d] = hv;
          else                  outV[(size_t)(bn * 1024 + i) * 64 + d] = hv;
        } else {
          int dist = row >> 2, b = row & 3, n = col >> 6, d = col & 63;
          outR[(size_t)((((b << 4) | n) * 1024 + dist)) * 64 + d] = f2bf(v);
        }
      }
}

// ---------------- final GEMM: AV @ Wob -> d_out f32 (128x64 tile, 2 blocks/CU) ----------------
__global__ __launch_bounds__(256, 2) void k_gemm2(const u16* __restrict__ A,
                                                  const u16* __restrict__ L,
                                                  float* __restrict__ out) {
  __shared__ u16 At[128 * 32];
  __shared__ u16 Lt[64 * 32];
  int m0 = blockIdx.x * 128, n0 = blockIdx.y * 64;
  int tid = threadIdx.x;
  int w = tid >> 6, lane = tid & 63;
  int lr = lane & 15, lg = lane >> 4;
  int wr = w >> 1, wc = w & 1;   // 2x2 waves over (128 rows, 64 cols)
  f32x4 acc[4][2] = {};

  for (int k0 = 0; k0 < 1024; k0 += 32) {
    for (int cc = 0; cc < 2; cc++) {
      int slot = cc * 256 + w * 64 + lane;
      int row = slot >> 2, ch = slot & 3;
      int sch = ch ^ ((row >> 1) & 3);
      int grow = m0 + row;
      int i = grow >> 2, b = grow & 3;
      int kk = k0 + sch * 8;
      int n = kk >> 6, d = kk & 63;
      gload16(A + (size_t)((((b << 4) | n) * 1024 + i)) * 64 + d,
              &At[(cc * 256 + w * 64) * 8]);
    }
    {
      int slot = w * 64 + lane;   // 256 slots cover 64 rows x 4 chunks
      int row = slot >> 2, ch = slot & 3;
      int sch = ch ^ ((row >> 1) & 3);
      gload16(L + (size_t)(n0 + row) * 1024 + k0 + sch * 8, &Lt[(w * 64) * 8]);
    }
    __syncthreads();
    short8 af[4], bfr[2];
    for (int mt = 0; mt < 4; mt++) {
      int rr = wr * 64 + mt * 16 + lr;
      af[mt] = *reinterpret_cast<const short8*>(&At[rr * 32 + ((lg ^ ((rr >> 1) & 3)) * 8)]);
    }
    for (int ct = 0; ct < 2; ct++) {
      int rr = wc * 32 + ct * 16 + lr;
      bfr[ct] = *reinterpret_cast<const short8*>(&Lt[rr * 32 + ((lg ^ ((rr >> 1) & 3)) * 8)]);
    }
    for (int mt = 0; mt < 4; mt++)
      for (int ct = 0; ct < 2; ct++)
        acc[mt][ct] = MFMA(af[mt], bfr[ct], acc[mt][ct]);
    __syncthreads();
  }

  for (int mt = 0; mt < 4; mt++)
    for (int ct = 0; ct < 2; ct++)
      for (int r = 0; r < 4; r++) {
        int row = m0 + wr * 64 + mt * 16 + lg * 4 + r;
        int col = n0 + wc * 32 + ct * 16 + lr;
        out[(size_t)row * 1024 + col] = acc[mt][ct][r];
      }
}

// ---------------- split-KV flash attention, 2-phase async LDS pipeline ----------------
// (round-12 structure; __syncthreads alone drains vmcnt per ISA semantics,
// so no explicit inline-asm wait at loop top.)
__global__ __launch_bounds__(256, 2) void k_attn3(
    const u16* __restrict__ Q, const u16* __restrict__ K, const u16* __restrict__ VT,
    const u16* __restrict__ R, const float* __restrict__ ef,
    const u64* __restrict__ dpw, const float* __restrict__ rwb,
    const float* __restrict__ rrb, float* __restrict__ lsb, u16* __restrict__ pO,
    u16* __restrict__ AV) {
  __shared__ u16 sK[2][64][64];
  __shared__ u16 sV[2][64][64];
  __shared__ u16 sR[2][128][64];
  __shared__ u16 p_lds[4][16][64];
  int f = blockIdx.x + 40 * blockIdx.y;
  int wg = (f & 7) * 320 + (f >> 3);
  int bn = wg / 40;
  int cid = 39 - (wg - bn * 40);       // logical chunk id; 4-tile chunks dispatch first
  int b = bn >> 4, n = bn & 15;
  int g = (cid < 4) ? 0 : (cid < 12) ? 1 : (cid < 24) ? 2 : 3;
  int off = cid - 2 * g * (g + 1);
  int qt = 4 * g + off / (g + 1);
  int jc = off % (g + 1);
  int ntiles = (jc < g) ? 4 : (qt + 1 - 4 * g);
  int jt0 = jc * 4;
  int tid = threadIdx.x;
  int w = tid >> 6, lane = tid & 63;
  int lr = lane & 15, lg = lane >> 4;
  int qbase = qt * 64 + w * 16;
  int sub = lane >> 3, ch = lane & 7;
  int cs = (ch ^ sub) * 8;
  int r8 = lr & 7;

  auto stage = [&](int bi, int j0) {
    int rbase = qt * 64 - j0 - 63;
#pragma unroll
    for (int q = 0; q < 2; q++) {
      int row = w * 16 + q * 8 + sub;
      gload16(K + (size_t)((bn << 10) + j0 + row) * 64 + cs, &sK[bi][w * 16 + q * 8][0]);
      gload16(VT + (((size_t)((bn << 6) + row)) << 10) + j0 + cs, &sV[bi][w * 16 + q * 8][0]);
    }
#pragma unroll
    for (int q = 0; q < 4; q++) {
      int pr = w * 32 + q * 8 + sub;
      int ridx = rbase + pr;
      ridx = ridx < 0 ? 0 : (ridx > 1023 ? 1023 : ridx);
      gload16(R + (size_t)((bn << 10) + ridx) * 64 + cs, &sR[bi][w * 32 + q * 8][0]);
    }
  };

  stage(0, jt0 * 64);

  const u64* dwbase = dpw + ((size_t)((b << 10) + qbase + lg * 4) << 4);
  u64 dwc[4], dwn[4] = {0, 0, 0, 0};
#pragma unroll
  for (int r = 0; r < 4; r++) dwc[r] = dwbase[(r << 4) + jt0];

  const float QS = 0.125f * LOG2E;
  short8 qw[2], qr[2];
  for (int ks = 0; ks < 2; ks++) {
    short8 qv = *reinterpret_cast<const short8*>(
        &Q[(size_t)((bn << 10) + qbase + lr) * 64 + ks * 32 + lg * 8]);
    short8 aa, bb;
    for (int e = 0; e < 8; e++) {
      int d = ks * 32 + lg * 8 + e;
      float fq = bf2f((u16)qv[e]);
      aa[e] = (short)f2bf((fq + rwb[n * 64 + d]) * QS);
      bb[e] = (short)f2bf((fq + rrb[n * 64 + d]) * QS);
    }
    qw[ks] = aa;
    qr[ks] = bb;
  }
  short8 ones;
#pragma unroll
  for (int e = 0; e < 8; e++) ones[e] = (short)0x3F80;  // bf16 1.0
  float de[4];
  for (int r = 0; r < 4; r++)
    de[r] = ef[(bn << 10) + qbase + lg * 4 + r];
  float lsum[4] = {0.f, 0.f, 0.f, 0.f};
  f32x4 Oacc[4] = {};

  for (int t = 0; t < ntiles; t++) {
    int jt = jt0 + t;
    int j0 = jt * 64;
    int bi = t & 1;
    __syncthreads();   // drains vmcnt+lgkm (compiler-emitted) -> buf[bi] ready
    if (t + 1 < ntiles) {
      stage(bi ^ 1, j0 + 64);
#pragma unroll
      for (int r = 0; r < 4; r++) dwn[r] = dwbase[(r << 4) + jt + 1];
    }

    // AC + BD MFMA cluster from LDS
    f32x4 sacc[4] = {};
    f32x4 tacc[5] = {};
    __builtin_amdgcn_s_setprio(1);
#pragma unroll
    for (int ks = 0; ks < 2; ks++) {
#pragma unroll
      for (int ct = 0; ct < 4; ct++) {
        short8 kb = *reinterpret_cast<const short8*>(
            &sK[bi][ct * 16 + lr][((ks * 4 + lg) ^ r8) * 8]);
        sacc[ct] = MFMA(qw[ks], kb, sacc[ct]);
      }
#pragma unroll
      for (int ct = 0; ct < 5; ct++) {
        short8 rb = *reinterpret_cast<const short8*>(
            &sR[bi][w * 16 + ct * 16 + lr][((ks * 4 + lg) ^ r8) * 8]);
        tacc[ct] = MFMA(qr[ks], rb, tacc[ct]);
      }
    }
    __builtin_amdgcn_s_setprio(0);

    // shear + score assembly + exp (m == 0, e0 dropped)
    bool diag = (jt == qt);
#pragma unroll
    for (int r = 0; r < 4; r++) {
      int ii = lg * 4 + r;
      int C0 = 63 + ii - lr;
      int sl = (lg << 4) | (C0 & 15);
      bool hi = (C0 >> 4) == 3;
      float tp0 = __shfl(tacc[0][r], sl);
      float tp1 = __shfl(tacc[1][r], sl);
      float tp2 = __shfl(tacc[2][r], sl);
      float tp3 = __shfl(tacc[3][r], sl);
      float tp4 = __shfl(tacc[4][r], sl);
#pragma unroll
      for (int ct = 0; ct < 4; ct++) {
        float bd;
        if (ct == 0)      bd = hi ? tp3 : tp4;
        else if (ct == 1) bd = hi ? tp2 : tp3;
        else if (ct == 2) bd = hi ? tp1 : tp2;
        else              bd = hi ? tp0 : tp1;
        float s = sacc[ct][r] + bd;
        int jj = ct * 16 + lr;
        if ((dwc[r] >> jj) & 1) s += de[r];
        if (diag && jj > w * 16 + ii) s = -1.0e30f;
        sacc[ct][r] = exp2f(s);
      }
    }
    // P -> LDS bf16 via cvt_pk pairs (per-wave region, XOR swizzle)
#pragma unroll
    for (int r = 0; r < 4; r++) {
      int ii = lg * 4 + r;
      int sw = (ii & 7) << 3;
      unsigned a01 = cvt_pk(sacc[0][r], sacc[1][r]);
      unsigned a23 = cvt_pk(sacc[2][r], sacc[3][r]);
      p_lds[w][ii][lr ^ sw]        = (u16)a01;
      p_lds[w][ii][(16 + lr) ^ sw] = (u16)(a01 >> 16);
      p_lds[w][ii][(32 + lr) ^ sw] = (u16)a23;
      p_lds[w][ii][(48 + lr) ^ sw] = (u16)(a23 >> 16);
    }
    // PV from staged sV + ones-MFMA row-sum
    f32x4 so = {};
    __builtin_amdgcn_s_setprio(1);
#pragma unroll
    for (int ks = 0; ks < 2; ks++) {
      int chunk = ks * 4 + lg;
      short8 afr = *reinterpret_cast<const short8*>(&p_lds[w][lr][(chunk ^ (lr & 7)) * 8]);
      so = MFMA(afr, ones, so);
#pragma unroll
      for (int dt = 0; dt < 4; dt++) {
        short8 vb = *reinterpret_cast<const short8*>(
            &sV[bi][dt * 16 + lr][((ks * 4 + lg) ^ r8) * 8]);
        Oacc[dt] = MFMA(afr, vb, Oacc[dt]);
      }
    }
    __builtin_amdgcn_s_setprio(0);
#pragma unroll
    for (int r = 0; r < 4; r++) lsum[r] += so[r];
#pragma unroll
    for (int r = 0; r < 4; r++) dwc[r] = dwn[r];
  }

  if (g == 0) {
    float inv[4];
#pragma unroll
    for (int r = 0; r < 4; r++) inv[r] = 1.0f / lsum[r];
#pragma unroll
    for (int dt = 0; dt < 4; dt++)
#pragma unroll
      for (int r = 0; r < 4; r++) {
        int qi = qbase + lg * 4 + r;
        AV[(size_t)((bn << 10) + qi) * 64 + dt * 16 + lr] = f2bf(Oacc[dt][r] * inv[r]);
      }
  } else {
    int pid = bn * 40 + cid;
    if (lr == 0)
#pragma unroll
      for (int r = 0; r < 4; r++) {
        int row = w * 16 + lg * 4 + r;
        lsb[(size_t)pid * 64 + row] = lsum[r];
      }
#pragma unroll
    for (int dt = 0; dt < 4; dt++)
#pragma unroll
      for (int r = 0; r < 4; r++) {
        int row = w * 16 + lg * 4 + r;
        pO[(size_t)pid * 4096 + row * 64 + dt * 16 + lr] = f2bf(Oacc[dt][r]);
      }
  }
}

// combine partials for qt >= 4 (exact, m == 0): grid (12, 64), block 256
__global__ void k_comb(const float* __restrict__ lsb, const u16* __restrict__ pO,
                       u16* __restrict__ AV) {
  __shared__ float sinv[64];
  int qt = blockIdx.x + 4, bn = blockIdx.y;
  int g = qt >> 2, nc = g + 1;
  int cbase = 2 * g * (g + 1) + (qt - 4 * g) * (g + 1);
  int pid0 = bn * 40 + cbase;
  int t = threadIdx.x;
  if (t < 64) {
    float L = 0.f;
    for (int c2 = 0; c2 < 4; c2++)
      if (c2 < nc) L += lsb[(size_t)(pid0 + c2) * 64 + t];
    sinv[t] = 1.0f / L;
  }
  __syncthreads();
  int dg = t & 7, rowg = t >> 3;
  for (int half = 0; half < 2; half++) {
    int ii = half * 32 + rowg;
    float o[8] = {0, 0, 0, 0, 0, 0, 0, 0};
    for (int c2 = 0; c2 < 4; c2++) {
      if (c2 >= nc) break;
      short8 pv = *reinterpret_cast<const short8*>(
          &pO[(size_t)(pid0 + c2) * 4096 + ii * 64 + dg * 8]);
      for (int e2 = 0; e2 < 8; e2++) o[e2] += bf2f((u16)pv[e2]);
    }
    float s = sinv[ii];
    short8 ov;
    for (int e2 = 0; e2 < 8; e2++) ov[e2] = (short)f2bf(o[e2] * s);
    *reinterpret_cast<short8*>(&AV[(size_t)((bn << 10) + qt * 64 + ii) * 64 + dg * 8]) = ov;
  }
}

// ---------------- launch ----------------

extern "C" void kernel_launch(void* const* d_in, const int* in_sizes, int n_in,
                              void* d_out, int out_size, void* d_ws, size_t ws_size,
                              hipStream_t stream) {
  const float* X    = (const float*)d_in[0];
  const float* pos  = (const float*)d_in[1];
  const float* segE = (const float*)d_in[2];
  const float* segM = (const float*)d_in[3];
  const float* rwb  = (const float*)d_in[4];
  const float* rrb  = (const float*)d_in[5];
  const float* rsb  = (const float*)d_in[6];
  const float* Wq = (const float*)d_in[8];
  const float* Wk = (const float*)d_in[9];
  const float* Wv = (const float*)d_in[10];
  const float* Wr = (const float*)d_in[11];
  const float* Wo = (const float*)d_in[12];

  char* ws = (char*)d_ws;
  u16* Xb   = (u16*)(ws);
  u16* Pb   = (u16*)(ws + (8L << 20));
  u16* WT3  = (u16*)(ws + (24L << 20));
  u16* WrT  = (u16*)(ws + (30L << 20));
  u16* Wob  = (u16*)(ws + (32L << 20));
  u16* Qb   = (u16*)(ws + (34L << 20));
  u16* Kb   = (u16*)(ws + (42L << 20));
  u16* VTb  = (u16*)(ws + (50L << 20));
  u16* Rb   = (u16*)(ws + (58L << 20));
  float* efb = (float*)(ws + (66L << 20));
  u64* dpwb = (u64*)(ws + (66L << 20) + (512L << 10));
  float* lsbb = (float*)(ws + (67L << 20));
  u16* pOb  = (u16*)(ws + (69L << 20));
  u16* AVb  = Xb;               // Xb dead after fused gemm launch
  u16* Vtmp = pOb;              // pO region idle until k_attn3

  k_prep<<<13317, 256, 0, stream>>>(pos, X, Wo, Wq, Wk, Wv, Wr,
                                    Pb, Xb, Wob, WT3, WrT);
  k_gemmF<<<dim3(32, 160), 256, 0, stream>>>(Xb, WT3, Pb, WrT, Qb, Kb, Vtmp, Rb,
                                             segM, dpwb);
  k_mid<<<1280, 256, 0, stream>>>(Vtmp, VTb, Qb, rsb, segE, efb);
  k_attn3<<<dim3(40, 64), 256, 0, stream>>>(Qb, Kb, VTb, Rb, efb, dpwb, rwb, rrb,
                                            lsbb, pOb, AVb);
  k_comb<<<dim3(12, 64), 256, 0, stream>>>(lsbb, pOb, AVb);
  k_gemm2<<<dim3(32, 16), 256, 0, stream>>>(AVb, Wob, (float*)d_out);
}

// Round 18
// 153.914 us; speedup vs baseline: 1.9942x; 1.9942x over previous
//
#include <hip/hip_runtime.h>
#include <hip/hip_bf16.h>
#include <stdint.h>

// S=1024, B=4, H=1024, N=16, D=64. Causal relative attention (TXL-style).
// ws layout (MB):
//   0  Xb   bf16 [4096][1024]          (later aliased as AVb)
//   8  Pb   bf16 rows0..4100 [.][1024] (pos)
//  24  WT3  bf16 [3072][1024]
//  30  WrT  bf16 [1024][1024]
//  32  Wob  bf16 [1024][1024]
//  34  Qb   bf16 [64bn][1024i][64d]
//  42  Kb   bf16 [64bn][1024j][64d]
//  50  VTb  bf16 [64bn][64d][1024j]
//  58  Rb   bf16 [64bn][1024dist][64d]   R[dist]=kr[S-dist]
//  66  efb  f32  [64bn][1024i]   de only, pre-scaled by 0.125*log2e
//  66.5 dpw u64  [4b][1024i][16jt]
//  67  lsb  f32  [2560pid][64row]        (l only; m == 0 globally)
//  69  pOb  bf16 [2560pid][64row][64d]   (21MB; base doubles as Vtmp before attn)
//
// m == 0 softmax (scores bounded by construction). e0 cancels in softmax.
// dpackw rides inside the fused-GEMM launch. NOTE: do NOT XCD-swizzle this
// heterogeneous grid — round-17 showed contiguous-chunk swizzle puts ALL GEMM
// blocks on 2 of 8 XCDs (4x serialization, +163us). Natural round-robin is
// already balanced per-kind.

typedef short short8 __attribute__((ext_vector_type(8)));
typedef __bf16 bf16x8 __attribute__((ext_vector_type(8)));
typedef float f32x4 __attribute__((ext_vector_type(4)));
typedef unsigned short u16;
typedef unsigned long long u64;

#define LOG2E 1.4426950408889634f

__device__ __forceinline__ u16 f2bf(float f) {
  union { float f; unsigned u; } v; v.f = f;
  unsigned u = v.u;
  u += 0x7fffu + ((u >> 16) & 1u);
  return (u16)(u >> 16);
}
__device__ __forceinline__ float bf2f(u16 h) {
  union { unsigned u; float f; } v; v.u = ((unsigned)h) << 16;
  return v.f;
}
__device__ __forceinline__ unsigned cvt_pk(float lo, float hi) {
  unsigned r;
  asm("v_cvt_pk_bf16_f32 %0, %1, %2" : "=v"(r) : "v"(lo), "v"(hi));
  return r;
}

__device__ __forceinline__ f32x4 MFMA(short8 a, short8 b, f32x4 c) {
  union { short8 s; bf16x8 v; } ua, ub;
  ua.s = a; ub.s = b;
  return __builtin_amdgcn_mfma_f32_16x16x32_bf16(ua.v, ub.v, c, 0, 0, 0);
}

__device__ __forceinline__ void gload16(const void* g, void* l) {
  __builtin_amdgcn_global_load_lds(
      (const __attribute__((address_space(1))) unsigned int*)g,
      (__attribute__((address_space(3))) unsigned int*)l, 16, 0, 0);
}

// ---------------- fused prep: cvt(pos,X,Wo) + transpose(Wq,Wk,Wv,Wr) ----------------
__global__ void k_prep(const float* __restrict__ pos, const float* __restrict__ X,
                       const float* __restrict__ Wo, const float* __restrict__ Wq,
                       const float* __restrict__ Wk, const float* __restrict__ Wv,
                       const float* __restrict__ Wr,
                       u16* __restrict__ Pb, u16* __restrict__ Xb, u16* __restrict__ Wob,
                       u16* __restrict__ WT3, u16* __restrict__ WrT) {
  int bid = blockIdx.x;
  int tid = threadIdx.x;
  if (bid < 9221) {
    const float* in; u16* out; int n, base;
    if (bid < 4101)      { in = pos; out = Pb;  n = 4198400; base = bid; }
    else if (bid < 8197) { in = X;   out = Xb;  n = 4194304; base = bid - 4101; }
    else                 { in = Wo;  out = Wob; n = 1048576; base = bid - 8197; }
    int i = (base * 256 + tid) * 4;
    if (i >= n) return;
    float4 f = *reinterpret_cast<const float4*>(in + i);
    ushort4 o;
    o.x = f2bf(f.x); o.y = f2bf(f.y); o.z = f2bf(f.z); o.w = f2bf(f.w);
    *reinterpret_cast<ushort4*>(out + i) = o;
  } else {
    __shared__ float tile[32][33];
    int tb = bid - 9221;
    int which = tb >> 10;
    int by = (tb >> 5) & 31, bx = tb & 31;
    const float* src = (which == 0) ? Wq : (which == 1) ? Wk : (which == 2) ? Wv : Wr;
    u16* dst = (which < 3) ? (WT3 + (size_t)which * 1048576) : WrT;
    int c0 = bx * 32, h0 = by * 32;
    int tx = tid & 31, ty = tid >> 5;
    for (int r = 0; r < 32; r += 8)
      tile[ty + r][tx] = src[(size_t)(h0 + ty + r) * 1024 + c0 + tx];
    __syncthreads();
    for (int r = 0; r < 32; r += 8)
      dst[(size_t)(c0 + ty + r) * 1024 + h0 + tx] = f2bf(tile[tx][ty + r]);
  }
}

// ---------------- fused mid: k_vt (blocks [0,1024)) + k_ef (blocks [1024,1280)) ----------------
__global__ void k_mid(const u16* __restrict__ V, u16* __restrict__ VT,
                      const u16* __restrict__ Q, const float* __restrict__ rsb,
                      const float* __restrict__ segE, float* __restrict__ ef) {
  int bid = blockIdx.x;
  int tid = threadIdx.x;
  if (bid < 1024) {
    __shared__ u16 t[64][68];
    int i0 = (bid & 15) * 64;
    int bn = bid >> 4;
    int tx = tid & 63, ty = tid >> 6;
#pragma unroll
    for (int q = 0; q < 16; q++) {
      int il = ty * 16 + q;
      t[il][tx] = V[(size_t)((bn << 10) + i0 + il) * 64 + tx];
    }
    __syncthreads();
#pragma unroll
    for (int q = 0; q < 16; q++) {
      int d = ty * 16 + q;
      VT[(((size_t)((bn << 6) | d)) << 10) + i0 + tx] = t[tx][d];
    }
  } else {
    int idx = (bid - 1024) * 256 + tid;
    int n = (idx >> 10) & 15;
    float s0 = 0.f, s1 = 0.f;
    const short8* qrow = reinterpret_cast<const short8*>(Q + ((size_t)idx) * 64);
#pragma unroll
    for (int c = 0; c < 8; c++) {
      short8 v = qrow[c];
#pragma unroll
      for (int e = 0; e < 8; e++) {
        int d = c * 8 + e;
        float qv = bf2f((u16)v[e]) + rsb[n * 64 + d];
        s0 += qv * segE[n * 64 + d];
        s1 += qv * segE[1024 + n * 64 + d];
      }
    }
    ef[idx] = (s1 - s0) * (0.125f * LOG2E);
  }
}

// ---------------- fused GEMM (128x128 tile) + dpackw riders (NO swizzle) ----------------
// grid (32, 160): y<24 mode0 (Xb@WT3 -> Q/K/V), y in [24,32) mode1
// (Pb remapped @ WrT -> Rb), y>=32 dpackw riders (seg_mat -> dpw).
__device__ __forceinline__ int srcA_g(int mode, int row, int kk) {
  if (mode == 0) return row * 1024 + kk;
  if (mode == 1) return ((1024 - (row >> 2)) * 4 + (row & 3)) * 1024 + kk;
  int i = row >> 2, b = row & 3, n = kk >> 6, d = kk & 63;
  return (((b << 4) | n) * 1024 + i) * 64 + d;
}

__global__ __launch_bounds__(256, 2) void k_gemmF(const u16* __restrict__ A0,
                                                  const u16* __restrict__ L0,
                                                  const u16* __restrict__ A1,
                                                  const u16* __restrict__ L1,
                                                  u16* __restrict__ outQ,
                                                  u16* __restrict__ outK,
                                                  u16* __restrict__ outV,
                                                  u16* __restrict__ outR,
                                                  const float* __restrict__ seg,
                                                  u64* __restrict__ dpw) {
  __shared__ u16 At[128 * 32];
  __shared__ u16 Lt[128 * 32];
  int tid = threadIdx.x;
  if (blockIdx.y >= 32) {
    // dpackw rider: one wave per (i,jt); coalesced 32B/lane, 4 ballots.
    int tb = (blockIdx.y - 32) * 32 + blockIdx.x;   // [0,4096)
    int W = tb * 4 + (tid >> 6);
    int lane = tid & 63;
    int jt = W & 15, i = W >> 4;
    const float4* p = reinterpret_cast<const float4*>(
        seg + ((size_t)((i << 10) + (jt << 6) + lane)) * 8);
    float4 a = p[0], bq = p[1];
    u64 m0 = __ballot(a.y != 0.f);
    u64 m1 = __ballot(a.w != 0.f);
    u64 m2 = __ballot(bq.y != 0.f);
    u64 m3 = __ballot(bq.w != 0.f);
    if (lane == 0) {
      int o = (i << 4) + jt;
      dpw[o] = m0;
      dpw[16384 + o] = m1;
      dpw[32768 + o] = m2;
      dpw[49152 + o] = m3;
    }
    return;
  }
  int mode, n0;
  const u16 *A, *L;
  if (blockIdx.y < 24) { mode = 0; n0 = blockIdx.y * 128; A = A0; L = L0; }
  else                 { mode = 1; n0 = (blockIdx.y - 24) * 128; A = A1; L = L1; }
  int m0 = blockIdx.x * 128;
  int w = tid >> 6, lane = tid & 63;
  int lr = lane & 15, lg = lane >> 4;
  int wr = w >> 1, wc = w & 1;
  f32x4 acc[4][4] = {};

  for (int k0 = 0; k0 < 1024; k0 += 32) {
    for (int cc = 0; cc < 2; cc++) {
      int slot = cc * 256 + w * 64 + lane;
      int row = slot >> 2, ch = slot & 3;
      int sch = ch ^ ((row >> 1) & 3);
      gload16(A + srcA_g(mode, m0 + row, k0 + sch * 8), &At[(cc * 256 + w * 64) * 8]);
      gload16(L + (size_t)(n0 + row) * 1024 + k0 + sch * 8, &Lt[(cc * 256 + w * 64) * 8]);
    }
    __syncthreads();
    short8 af[4], bfr[4];
    for (int mt = 0; mt < 4; mt++) {
      int rr = wr * 64 + mt * 16 + lr;
      af[mt] = *reinterpret_cast<const short8*>(&At[rr * 32 + ((lg ^ ((rr >> 1) & 3)) * 8)]);
    }
    for (int ct = 0; ct < 4; ct++) {
      int rr = wc * 64 + ct * 16 + lr;
      bfr[ct] = *reinterpret_cast<const short8*>(&Lt[rr * 32 + ((lg ^ ((rr >> 1) & 3)) * 8)]);
    }
    for (int mt = 0; mt < 4; mt++)
      for (int ct = 0; ct < 4; ct++)
        acc[mt][ct] = MFMA(af[mt], bfr[ct], acc[mt][ct]);
    __syncthreads();
  }

  for (int mt = 0; mt < 4; mt++)
    for (int ct = 0; ct < 4; ct++)
      for (int r = 0; r < 4; r++) {
        int row = m0 + wr * 64 + mt * 16 + lg * 4 + r;
        int col = n0 + wc * 64 + ct * 16 + lr;
        float v = acc[mt][ct][r];
        if (mode == 0) {
          int i = row >> 2, b = row & 3;
          int which = col >> 10, nd = col & 1023, n = nd >> 6, d = nd & 63;
          u16 hv = f2bf(v);
          int bn = (b << 4) | n;
          if (which == 0)       outQ[(size_t)(bn * 1024 + i) * 64 + d] = hv;
          else if (which == 1)  outK[(size_t)(bn * 1024 + i) * 64 + d] = hv;
          else                  outV[(size_t)(bn * 1024 + i) * 64 + d] = hv;
        } else {
          int dist = row >> 2, b = row & 3, n = col >> 6, d = col & 63;
          outR[(size_t)((((b << 4) | n) * 1024 + dist)) * 64 + d] = f2bf(v);
        }
      }
}

// ---------------- final GEMM: AV @ Wob -> d_out f32 (128x64 tile, 2 blocks/CU) ----------------
__global__ __launch_bounds__(256, 2) void k_gemm2(const u16* __restrict__ A,
                                                  const u16* __restrict__ L,
                                                  float* __restrict__ out) {
  __shared__ u16 At[128 * 32];
  __shared__ u16 Lt[64 * 32];
  int m0 = blockIdx.x * 128, n0 = blockIdx.y * 64;
  int tid = threadIdx.x;
  int w = tid >> 6, lane = tid & 63;
  int lr = lane & 15, lg = lane >> 4;
  int wr = w >> 1, wc = w & 1;   // 2x2 waves over (128 rows, 64 cols)
  f32x4 acc[4][2] = {};

  for (int k0 = 0; k0 < 1024; k0 += 32) {
    for (int cc = 0; cc < 2; cc++) {
      int slot = cc * 256 + w * 64 + lane;
      int row = slot >> 2, ch = slot & 3;
      int sch = ch ^ ((row >> 1) & 3);
      int grow = m0 + row;
      int i = grow >> 2, b = grow & 3;
      int kk = k0 + sch * 8;
      int n = kk >> 6, d = kk & 63;
      gload16(A + (size_t)((((b << 4) | n) * 1024 + i)) * 64 + d,
              &At[(cc * 256 + w * 64) * 8]);
    }
    {
      int slot = w * 64 + lane;   // 256 slots cover 64 rows x 4 chunks
      int row = slot >> 2, ch = slot & 3;
      int sch = ch ^ ((row >> 1) & 3);
      gload16(L + (size_t)(n0 + row) * 1024 + k0 + sch * 8, &Lt[(w * 64) * 8]);
    }
    __syncthreads();
    short8 af[4], bfr[2];
    for (int mt = 0; mt < 4; mt++) {
      int rr = wr * 64 + mt * 16 + lr;
      af[mt] = *reinterpret_cast<const short8*>(&At[rr * 32 + ((lg ^ ((rr >> 1) & 3)) * 8)]);
    }
    for (int ct = 0; ct < 2; ct++) {
      int rr = wc * 32 + ct * 16 + lr;
      bfr[ct] = *reinterpret_cast<const short8*>(&Lt[rr * 32 + ((lg ^ ((rr >> 1) & 3)) * 8)]);
    }
    for (int mt = 0; mt < 4; mt++)
      for (int ct = 0; ct < 2; ct++)
        acc[mt][ct] = MFMA(af[mt], bfr[ct], acc[mt][ct]);
    __syncthreads();
  }

  for (int mt = 0; mt < 4; mt++)
    for (int ct = 0; ct < 2; ct++)
      for (int r = 0; r < 4; r++) {
        int row = m0 + wr * 64 + mt * 16 + lg * 4 + r;
        int col = n0 + wc * 32 + ct * 16 + lr;
        out[(size_t)row * 1024 + col] = acc[mt][ct][r];
      }
}

// ---------------- split-KV flash attention, 2-phase async LDS pipeline ----------------
// (round-12 structure; __syncthreads alone drains vmcnt per ISA semantics.)
__global__ __launch_bounds__(256, 2) void k_attn3(
    const u16* __restrict__ Q, const u16* __restrict__ K, const u16* __restrict__ VT,
    const u16* __restrict__ R, const float* __restrict__ ef,
    const u64* __restrict__ dpw, const float* __restrict__ rwb,
    const float* __restrict__ rrb, float* __restrict__ lsb, u16* __restrict__ pO,
    u16* __restrict__ AV) {
  __shared__ u16 sK[2][64][64];
  __shared__ u16 sV[2][64][64];
  __shared__ u16 sR[2][128][64];
  __shared__ u16 p_lds[4][16][64];
  int f = blockIdx.x + 40 * blockIdx.y;
  int wg = (f & 7) * 320 + (f >> 3);
  int bn = wg / 40;
  int cid = 39 - (wg - bn * 40);       // logical chunk id; 4-tile chunks dispatch first
  int b = bn >> 4, n = bn & 15;
  int g = (cid < 4) ? 0 : (cid < 12) ? 1 : (cid < 24) ? 2 : 3;
  int off = cid - 2 * g * (g + 1);
  int qt = 4 * g + off / (g + 1);
  int jc = off % (g + 1);
  int ntiles = (jc < g) ? 4 : (qt + 1 - 4 * g);
  int jt0 = jc * 4;
  int tid = threadIdx.x;
  int w = tid >> 6, lane = tid & 63;
  int lr = lane & 15, lg = lane >> 4;
  int qbase = qt * 64 + w * 16;
  int sub = lane >> 3, ch = lane & 7;
  int cs = (ch ^ sub) * 8;
  int r8 = lr & 7;

  auto stage = [&](int bi, int j0) {
    int rbase = qt * 64 - j0 - 63;
#pragma unroll
    for (int q = 0; q < 2; q++) {
      int row = w * 16 + q * 8 + sub;
      gload16(K + (size_t)((bn << 10) + j0 + row) * 64 + cs, &sK[bi][w * 16 + q * 8][0]);
      gload16(VT + (((size_t)((bn << 6) + row)) << 10) + j0 + cs, &sV[bi][w * 16 + q * 8][0]);
    }
#pragma unroll
    for (int q = 0; q < 4; q++) {
      int pr = w * 32 + q * 8 + sub;
      int ridx = rbase + pr;
      ridx = ridx < 0 ? 0 : (ridx > 1023 ? 1023 : ridx);
      gload16(R + (size_t)((bn << 10) + ridx) * 64 + cs, &sR[bi][w * 32 + q * 8][0]);
    }
  };

  stage(0, jt0 * 64);

  const u64* dwbase = dpw + ((size_t)((b << 10) + qbase + lg * 4) << 4);
  u64 dwc[4], dwn[4] = {0, 0, 0, 0};
#pragma unroll
  for (int r = 0; r < 4; r++) dwc[r] = dwbase[(r << 4) + jt0];

  const float QS = 0.125f * LOG2E;
  short8 qw[2], qr[2];
  for (int ks = 0; ks < 2; ks++) {
    short8 qv = *reinterpret_cast<const short8*>(
        &Q[(size_t)((bn << 10) + qbase + lr) * 64 + ks * 32 + lg * 8]);
    short8 aa, bb;
    for (int e = 0; e < 8; e++) {
      int d = ks * 32 + lg * 8 + e;
      float fq = bf2f((u16)qv[e]);
      aa[e] = (short)f2bf((fq + rwb[n * 64 + d]) * QS);
      bb[e] = (short)f2bf((fq + rrb[n * 64 + d]) * QS);
    }
    qw[ks] = aa;
    qr[ks] = bb;
  }
  short8 ones;
#pragma unroll
  for (int e = 0; e < 8; e++) ones[e] = (short)0x3F80;  // bf16 1.0
  float de[4];
  for (int r = 0; r < 4; r++)
    de[r] = ef[(bn << 10) + qbase + lg * 4 + r];
  float lsum[4] = {0.f, 0.f, 0.f, 0.f};
  f32x4 Oacc[4] = {};

  for (int t = 0; t < ntiles; t++) {
    int jt = jt0 + t;
    int j0 = jt * 64;
    int bi = t & 1;
    __syncthreads();   // compiler-emitted vmcnt(0)+lgkm(0) drain -> buf[bi] ready
    if (t + 1 < ntiles) {
      stage(bi ^ 1, j0 + 64);
#pragma unroll
      for (int r = 0; r < 4; r++) dwn[r] = dwbase[(r << 4) + jt + 1];
    }

    // AC + BD MFMA cluster from LDS
    f32x4 sacc[4] = {};
    f32x4 tacc[5] = {};
    __builtin_amdgcn_s_setprio(1);
#pragma unroll
    for (int ks = 0; ks < 2; ks++) {
#pragma unroll
      for (int ct = 0; ct < 4; ct++) {
        short8 kb = *reinterpret_cast<const short8*>(
            &sK[bi][ct * 16 + lr][((ks * 4 + lg) ^ r8) * 8]);
        sacc[ct] = MFMA(qw[ks], kb, sacc[ct]);
      }
#pragma unroll
      for (int ct = 0; ct < 5; ct++) {
        short8 rb = *reinterpret_cast<const short8*>(
            &sR[bi][w * 16 + ct * 16 + lr][((ks * 4 + lg) ^ r8) * 8]);
        tacc[ct] = MFMA(qr[ks], rb, tacc[ct]);
      }
    }
    __builtin_amdgcn_s_setprio(0);

    // shear + score assembly + exp (m == 0, e0 dropped)
    bool diag = (jt == qt);
#pragma unroll
    for (int r = 0; r < 4; r++) {
      int ii = lg * 4 + r;
      int C0 = 63 + ii - lr;
      int sl = (lg << 4) | (C0 & 15);
      bool hi = (C0 >> 4) == 3;
      float tp0 = __shfl(tacc[0][r], sl);
      float tp1 = __shfl(tacc[1][r], sl);
      float tp2 = __shfl(tacc[2][r], sl);
      float tp3 = __shfl(tacc[3][r], sl);
      float tp4 = __shfl(tacc[4][r], sl);
#pragma unroll
      for (int ct = 0; ct < 4; ct++) {
        float bd;
        if (ct == 0)      bd = hi ? tp3 : tp4;
        else if (ct == 1) bd = hi ? tp2 : tp3;
        else if (ct == 2) bd = hi ? tp1 : tp2;
        else              bd = hi ? tp0 : tp1;
        float s = sacc[ct][r] + bd;
        int jj = ct * 16 + lr;
        if ((dwc[r] >> jj) & 1) s += de[r];
        if (diag && jj > w * 16 + ii) s = -1.0e30f;
        sacc[ct][r] = exp2f(s);
      }
    }
    // P -> LDS bf16 via cvt_pk pairs (per-wave region, XOR swizzle)
#pragma unroll
    for (int r = 0; r < 4; r++) {
      int ii = lg * 4 + r;
      int sw = (ii & 7) << 3;
      unsigned a01 = cvt_pk(sacc[0][r], sacc[1][r]);
      unsigned a23 = cvt_pk(sacc[2][r], sacc[3][r]);
      p_lds[w][ii][lr ^ sw]        = (u16)a01;
      p_lds[w][ii][(16 + lr) ^ sw] = (u16)(a01 >> 16);
      p_lds[w][ii][(32 + lr) ^ sw] = (u16)a23;
      p_lds[w][ii][(48 + lr) ^ sw] = (u16)(a23 >> 16);
    }
    // PV from staged sV + ones-MFMA row-sum
    f32x4 so = {};
    __builtin_amdgcn_s_setprio(1);
#pragma unroll
    for (int ks = 0; ks < 2; ks++) {
      int chunk = ks * 4 + lg;
      short8 afr = *reinterpret_cast<const short8*>(&p_lds[w][lr][(chunk ^ (lr & 7)) * 8]);
      so = MFMA(afr, ones, so);
#pragma unroll
      for (int dt = 0; dt < 4; dt++) {
        short8 vb = *reinterpret_cast<const short8*>(
            &sV[bi][dt * 16 + lr][((ks * 4 + lg) ^ r8) * 8]);
        Oacc[dt] = MFMA(afr, vb, Oacc[dt]);
      }
    }
    __builtin_amdgcn_s_setprio(0);
#pragma unroll
    for (int r = 0; r < 4; r++) lsum[r] += so[r];
#pragma unroll
    for (int r = 0; r < 4; r++) dwc[r] = dwn[r];
  }

  if (g == 0) {
    float inv[4];
#pragma unroll
    for (int r = 0; r < 4; r++) inv[r] = 1.0f / lsum[r];
#pragma unroll
    for (int dt = 0; dt < 4; dt++)
#pragma unroll
      for (int r = 0; r < 4; r++) {
        int qi = qbase + lg * 4 + r;
        AV[(size_t)((bn << 10) + qi) * 64 + dt * 16 + lr] = f2bf(Oacc[dt][r] * inv[r]);
      }
  } else {
    int pid = bn * 40 + cid;
    if (lr == 0)
#pragma unroll
      for (int r = 0; r < 4; r++) {
        int row = w * 16 + lg * 4 + r;
        lsb[(size_t)pid * 64 + row] = lsum[r];
      }
#pragma unroll
    for (int dt = 0; dt < 4; dt++)
#pragma unroll
      for (int r = 0; r < 4; r++) {
        int row = w * 16 + lg * 4 + r;
        pO[(size_t)pid * 4096 + row * 64 + dt * 16 + lr] = f2bf(Oacc[dt][r]);
      }
  }
}

// combine partials for qt >= 4 (exact, m == 0): grid (12, 64), block 256
__global__ void k_comb(const float* __restrict__ lsb, const u16* __restrict__ pO,
                       u16* __restrict__ AV) {
  __shared__ float sinv[64];
  int qt = blockIdx.x + 4, bn = blockIdx.y;
  int g = qt >> 2, nc = g + 1;
  int cbase = 2 * g * (g + 1) + (qt - 4 * g) * (g + 1);
  int pid0 = bn * 40 + cbase;
  int t = threadIdx.x;
  if (t < 64) {
    float L = 0.f;
    for (int c2 = 0; c2 < 4; c2++)
      if (c2 < nc) L += lsb[(size_t)(pid0 + c2) * 64 + t];
    sinv[t] = 1.0f / L;
  }
  __syncthreads();
  int dg = t & 7, rowg = t >> 3;
  for (int half = 0; half < 2; half++) {
    int ii = half * 32 + rowg;
    float o[8] = {0, 0, 0, 0, 0, 0, 0, 0};
    for (int c2 = 0; c2 < 4; c2++) {
      if (c2 >= nc) break;
      short8 pv = *reinterpret_cast<const short8*>(
          &pO[(size_t)(pid0 + c2) * 4096 + ii * 64 + dg * 8]);
      for (int e2 = 0; e2 < 8; e2++) o[e2] += bf2f((u16)pv[e2]);
    }
    float s = sinv[ii];
    short8 ov;
    for (int e2 = 0; e2 < 8; e2++) ov[e2] = (short)f2bf(o[e2] * s);
    *reinterpret_cast<short8*>(&AV[(size_t)((bn << 10) + qt * 64 + ii) * 64 + dg * 8]) = ov;
  }
}

// ---------------- launch ----------------

extern "C" void kernel_launch(void* const* d_in, const int* in_sizes, int n_in,
                              void* d_out, int out_size, void* d_ws, size_t ws_size,
                              hipStream_t stream) {
  const float* X    = (const float*)d_in[0];
  const float* pos  = (const float*)d_in[1];
  const float* segE = (const float*)d_in[2];
  const float* segM = (const float*)d_in[3];
  const float* rwb  = (const float*)d_in[4];
  const float* rrb  = (const float*)d_in[5];
  const float* rsb  = (const float*)d_in[6];
  const float* Wq = (const float*)d_in[8];
  const float* Wk = (const float*)d_in[9];
  const float* Wv = (const float*)d_in[10];
  const float* Wr = (const float*)d_in[11];
  const float* Wo = (const float*)d_in[12];

  char* ws = (char*)d_ws;
  u16* Xb   = (u16*)(ws);
  u16* Pb   = (u16*)(ws + (8L << 20));
  u16* WT3  = (u16*)(ws + (24L << 20));
  u16* WrT  = (u16*)(ws + (30L << 20));
  u16* Wob  = (u16*)(ws + (32L << 20));
  u16* Qb   = (u16*)(ws + (34L << 20));
  u16* Kb   = (u16*)(ws + (42L << 20));
  u16* VTb  = (u16*)(ws + (50L << 20));
  u16* Rb   = (u16*)(ws + (58L << 20));
  float* efb = (float*)(ws + (66L << 20));
  u64* dpwb = (u64*)(ws + (66L << 20) + (512L << 10));
  float* lsbb = (float*)(ws + (67L << 20));
  u16* pOb  = (u16*)(ws + (69L << 20));
  u16* AVb  = Xb;               // Xb dead after fused gemm launch
  u16* Vtmp = pOb;              // pO region idle until k_attn3

  k_prep<<<13317, 256, 0, stream>>>(pos, X, Wo, Wq, Wk, Wv, Wr,
                                    Pb, Xb, Wob, WT3, WrT);
  k_gemmF<<<dim3(32, 160), 256, 0, stream>>>(Xb, WT3, Pb, WrT, Qb, Kb, Vtmp, Rb,
                                             segM, dpwb);
  k_mid<<<1280, 256, 0, stream>>>(Vtmp, VTb, Qb, rsb, segE, efb);
  k_attn3<<<dim3(40, 64), 256, 0, stream>>>(Qb, Kb, VTb, Rb, efb, dpwb, rwb, rrb,
                                            lsbb, pOb, AVb);
  k_comb<<<dim3(12, 64), 256, 0, stream>>>(lsbb, pOb, AVb);
  k_gemm2<<<dim3(32, 16), 256, 0, stream>>>(AVb, Wob, (float*)d_out);
}